// Round 1
// baseline (1465.075 us; speedup 1.0000x reference)
//
#include <hip/hip_runtime.h>
#include <math.h>

#define BB 64
#define KVLEN 2048
#define HID 4096
#define NH 32
#define NKVH 8
#define DH 128
#define GQ 4
#define QKV_N ((NH + 2 * NKVH) * DH) /* 6144 */

// ---------------- bias broadcast init ----------------
__global__ __launch_bounds__(256) void bias_init(float4* __restrict__ dst,
                                                 const float4* __restrict__ bias,
                                                 int ncols4, int total4) {
  int i = blockIdx.x * 256 + threadIdx.x;
  if (i < total4) dst[i] = bias[i % ncols4];
}

// ---------------- skinny GEMM: out[64][N] (+)= A[64][K-chunk] @ W[K-chunk][N] ----------------
// lane = m (row), wave owns 8 columns; W loads are wave-uniform -> s_load.
__global__ __launch_bounds__(256) void gemm_skinny(const float* __restrict__ A,
                                                   const float* __restrict__ W,
                                                   float* __restrict__ out,
                                                   int N, int K, int kchunk) {
  int lane = threadIdx.x & 63;
  int wave = __builtin_amdgcn_readfirstlane((int)(threadIdx.x >> 6));
  int n0 = blockIdx.x * 32 + wave * 8;
  int k0 = blockIdx.y * kchunk;
  const float* Arow = A + (size_t)lane * K + k0;
  const float* Wp = W + (size_t)k0 * N + n0;
  float acc[8] = {0.f, 0.f, 0.f, 0.f, 0.f, 0.f, 0.f, 0.f};
  for (int k = 0; k < kchunk; k += 8) {
    float4 a4a = *(const float4*)(Arow + k);
    float4 a4b = *(const float4*)(Arow + k + 4);
    float av[8] = {a4a.x, a4a.y, a4a.z, a4a.w, a4b.x, a4b.y, a4b.z, a4b.w};
    const float* w0 = Wp + (size_t)k * N;
#pragma unroll
    for (int kk = 0; kk < 8; ++kk) {
      const float* wr = w0 + (size_t)kk * N;
#pragma unroll
      for (int j = 0; j < 8; ++j)
        acc[j] = fmaf(av[kk], wr[j], acc[j]);
    }
  }
  float* op = out + (size_t)lane * N + n0;
#pragma unroll
  for (int j = 0; j < 8; ++j) atomicAdd(op + j, acc[j]);
}

// ---------------- RoPE (neox, rotate halves) in-place on q (+scale) and k_new ----------------
__global__ __launch_bounds__(256) void rope_kernel(float* __restrict__ qkv,
                                                   const int* __restrict__ positions) {
  int idx = blockIdx.x * 256 + threadIdx.x; // B * 40 heads * 64 pairs
  int d = idx & 63;
  int hb = idx >> 6;
  int head = hb % (NH + NKVH);
  int b = hb / (NH + NKVH);
  float* base = qkv + (size_t)b * QKV_N + (size_t)head * DH;
  // inv_freq = 10000^(-d/64) = 2^(-d * log2(10000)/64), computed in fp64
  double inv_freq = exp2(-(double)d * (13.287712379549449 / 64.0));
  double ang = (double)positions[b] * inv_freq;
  double sd, cd;
  sincos(ang, &sd, &cd);
  float c = (float)cd, s = (float)sd;
  float x1 = base[d], x2 = base[d + 64];
  float scale = (head < NH) ? 0.08838834764831845f : 1.0f; // fold SCALE into q
  base[d] = (x1 * c - x2 * s) * scale;
  base[d + 64] = (x2 * c + x1 * s) * scale;
}

// ---------------- GQA decode attention: one block per (b, kvh) ----------------
__global__ __launch_bounds__(256) void attn_kernel(const float* __restrict__ kc,
                                                   const float* __restrict__ vc,
                                                   const float* __restrict__ qkv,
                                                   float* __restrict__ attn) {
  int b = blockIdx.x >> 3;
  int kvh = blockIdx.x & 7;
  int tid = threadIdx.x;
  int lane = tid & 63;
  int wave = tid >> 6;

  __shared__ float q_s[4][DH];
  __shared__ float p_s[(KVLEN + 1) * 4]; // [s][h]
  __shared__ float red[4][4];            // [wave][h]
  __shared__ float4 comb[128];

  // load the 4 q heads of this kv group (already scaled by SCALE)
  const float* qb = qkv + (size_t)b * QKV_N + (size_t)(kvh * GQ) * DH;
  for (int i = tid; i < 4 * DH; i += 256) q_s[i >> 7][i & 127] = qb[i];
  __syncthreads();

  // ---- pass 1: scores for cached positions, kept in registers ----
  const float* Kb = kc + ((size_t)b * KVLEN * NKVH + kvh) * DH;
  float sc[8][4];
#pragma unroll
  for (int i = 0; i < 8; ++i) {
    int s = i * 256 + tid;
    const float4* kr = (const float4*)(Kb + (size_t)s * (NKVH * DH));
    float a0 = 0.f, a1 = 0.f, a2 = 0.f, a3 = 0.f;
#pragma unroll 8
    for (int d4 = 0; d4 < 32; ++d4) {
      float4 k4 = kr[d4];
      float4 q0 = *(const float4*)&q_s[0][d4 * 4];
      float4 q1 = *(const float4*)&q_s[1][d4 * 4];
      float4 q2 = *(const float4*)&q_s[2][d4 * 4];
      float4 q3 = *(const float4*)&q_s[3][d4 * 4];
      a0 = fmaf(k4.x, q0.x, fmaf(k4.y, q0.y, fmaf(k4.z, q0.z, fmaf(k4.w, q0.w, a0))));
      a1 = fmaf(k4.x, q1.x, fmaf(k4.y, q1.y, fmaf(k4.z, q1.z, fmaf(k4.w, q1.w, a1))));
      a2 = fmaf(k4.x, q2.x, fmaf(k4.y, q2.y, fmaf(k4.z, q2.z, fmaf(k4.w, q2.w, a2))));
      a3 = fmaf(k4.x, q3.x, fmaf(k4.y, q3.y, fmaf(k4.z, q3.z, fmaf(k4.w, q3.w, a3))));
    }
    sc[i][0] = a0; sc[i][1] = a1; sc[i][2] = a2; sc[i][3] = a3;
  }

  // ---- new-token (s = KV) scores by wave 0 ----
  if (wave == 0) {
    const float* kn = qkv + (size_t)b * QKV_N + NH * DH + (size_t)kvh * DH;
    float k1v = kn[lane], k2v = kn[lane + 64];
    float pn[4];
#pragma unroll
    for (int h = 0; h < 4; ++h)
      pn[h] = k1v * q_s[h][lane] + k2v * q_s[h][lane + 64];
#pragma unroll
    for (int off = 32; off > 0; off >>= 1) {
#pragma unroll
      for (int h = 0; h < 4; ++h) pn[h] += __shfl_down(pn[h], off);
    }
    if (lane == 0) {
#pragma unroll
      for (int h = 0; h < 4; ++h) p_s[KVLEN * 4 + h] = pn[h];
    }
  }
  __syncthreads();

  // ---- block max ----
  float mxl[4];
#pragma unroll
  for (int h = 0; h < 4; ++h) mxl[h] = p_s[KVLEN * 4 + h];
#pragma unroll
  for (int i = 0; i < 8; ++i)
#pragma unroll
    for (int h = 0; h < 4; ++h) mxl[h] = fmaxf(mxl[h], sc[i][h]);
#pragma unroll
  for (int off = 32; off > 0; off >>= 1) {
#pragma unroll
    for (int h = 0; h < 4; ++h) mxl[h] = fmaxf(mxl[h], __shfl_xor(mxl[h], off));
  }
  if (lane == 0) {
#pragma unroll
    for (int h = 0; h < 4; ++h) red[wave][h] = mxl[h];
  }
  __syncthreads();
  float mx[4];
#pragma unroll
  for (int h = 0; h < 4; ++h)
    mx[h] = fmaxf(fmaxf(red[0][h], red[1][h]), fmaxf(red[2][h], red[3][h]));
  __syncthreads(); // before red reuse

  // ---- exp + block sum; write P to LDS ----
  float ls[4] = {0.f, 0.f, 0.f, 0.f};
#pragma unroll
  for (int i = 0; i < 8; ++i) {
    int s = i * 256 + tid;
#pragma unroll
    for (int h = 0; h < 4; ++h) {
      float e = __expf(sc[i][h] - mx[h]);
      p_s[s * 4 + h] = e;
      ls[h] += e;
    }
  }
  if (tid < 4) {
    float e = __expf(p_s[KVLEN * 4 + tid] - mx[tid]);
    p_s[KVLEN * 4 + tid] = e;
    ls[tid] += e;
  }
#pragma unroll
  for (int off = 32; off > 0; off >>= 1) {
#pragma unroll
    for (int h = 0; h < 4; ++h) ls[h] += __shfl_xor(ls[h], off);
  }
  if (lane == 0) {
#pragma unroll
    for (int h = 0; h < 4; ++h) red[wave][h] = ls[h];
  }
  __syncthreads();
  float inv[4];
#pragma unroll
  for (int h = 0; h < 4; ++h)
    inv[h] = 1.0f / (red[0][h] + red[1][h] + red[2][h] + red[3][h]);

  // ---- pass 3: O = P @ V. threads = (half, h, d4) ----
  int half = tid >> 7;
  int r = tid & 127;
  int h = r >> 5;
  int d4 = r & 31;
  const float4* Vb = (const float4*)(vc + ((size_t)b * KVLEN * NKVH + kvh) * DH);
  float4 acc = {0.f, 0.f, 0.f, 0.f};
  int s0 = half * 1024;
  int s1 = s0 + 1024;
#pragma unroll 4
  for (int s = s0; s < s1; ++s) {
    float4 v4 = Vb[(size_t)s * (NKVH * DH / 4) + d4];
    float p = p_s[s * 4 + h];
    acc.x = fmaf(p, v4.x, acc.x);
    acc.y = fmaf(p, v4.y, acc.y);
    acc.z = fmaf(p, v4.z, acc.z);
    acc.w = fmaf(p, v4.w, acc.w);
  }
  if (half) { // s = KV: v_new from qkv buffer
    const float* vn = qkv + (size_t)b * QKV_N + (NH + NKVH) * DH + (size_t)kvh * DH;
    float4 v4 = *(const float4*)(vn + d4 * 4);
    float p = p_s[KVLEN * 4 + h];
    acc.x = fmaf(p, v4.x, acc.x);
    acc.y = fmaf(p, v4.y, acc.y);
    acc.z = fmaf(p, v4.z, acc.z);
    acc.w = fmaf(p, v4.w, acc.w);
    comb[r] = acc;
  }
  __syncthreads();
  if (!half) {
    float4 o = comb[r];
    float iv = inv[h];
    o.x = (o.x + acc.x) * iv;
    o.y = (o.y + acc.y) * iv;
    o.z = (o.z + acc.z) * iv;
    o.w = (o.w + acc.w) * iv;
    ((float4*)(attn + (size_t)b * HID + (size_t)kvh * (GQ * DH)))[r] = o;
  }
}

extern "C" void kernel_launch(void* const* d_in, const int* in_sizes, int n_in,
                              void* d_out, int out_size, void* d_ws, size_t ws_size,
                              hipStream_t stream) {
  (void)in_sizes; (void)n_in; (void)out_size; (void)ws_size;
  const float* h    = (const float*)d_in[0];
  const float* kc   = (const float*)d_in[1];
  const float* vc   = (const float*)d_in[2];
  const int*   pos  = (const int*)d_in[3];
  const float* Wqkv = (const float*)d_in[4];
  const float* bqkv = (const float*)d_in[5];
  const float* Wo   = (const float*)d_in[6];
  const float* bo   = (const float*)d_in[7];
  float* out = (float*)d_out;

  float* qkv  = (float*)d_ws;                     // [64][6144]
  float* attn = qkv + (size_t)BB * QKV_N;         // [64][4096]

  // 1. qkv <- bias (atomic accumulation target)
  bias_init<<<(BB * QKV_N / 4) / 256, 256, 0, stream>>>(
      (float4*)qkv, (const float4*)bqkv, QKV_N / 4, BB * QKV_N / 4);

  // 2. qkv += h @ Wqkv   (N=6144, K=4096, k-split 4)
  dim3 g1(QKV_N / 32, 4);
  gemm_skinny<<<g1, 256, 0, stream>>>(h, Wqkv, qkv, QKV_N, HID, HID / 4);

  // 3. RoPE on q (+SCALE) and k_new, in place
  rope_kernel<<<(BB * (NH + NKVH) * 64) / 256, 256, 0, stream>>>(qkv, pos);

  // 4. attention -> attn[64][4096]
  attn_kernel<<<BB * NKVH, 256, 0, stream>>>(kc, vc, qkv, attn);

  // 5. out <- bo
  bias_init<<<(BB * HID / 4) / 256, 256, 0, stream>>>(
      (float4*)out, (const float4*)bo, HID / 4, BB * HID / 4);

  // 6. out += attn @ Wo  (N=4096, K=4096, k-split 4)
  dim3 g2(HID / 32, 4);
  gemm_skinny<<<g2, 256, 0, stream>>>(attn, Wo, out, HID, HID, HID / 4);
}